// Round 11
// baseline (247.662 us; speedup 1.0000x reference)
//
#include <hip/hip_runtime.h>
#include <hip/hip_bf16.h>
#include <hip/hip_cooperative_groups.h>
#include <stdint.h>

namespace cg = cooperative_groups;

// Problem constants (N,C,H,W = 4,128,64,64)
#define NB 4
#define CH 128
#define LL 4096   // H*W

typedef __attribute__((ext_vector_type(8))) short short8;   // 8 bf16 MFMA A/B frag (4 VGPR)
typedef __attribute__((ext_vector_type(4))) short short4b;  // 4 bf16 (8B)
typedef __attribute__((ext_vector_type(4))) float floatx4;  // 16x16 C/D frag
typedef __attribute__((ext_vector_type(16))) float floatx16; // 32x32 C/D frag

// Frag-major layout (verified R9-R13): element (row r, k) of 16-wide tile t:
//   t*2048 + (k>>5)*512 + ((k>>3)&3)*128 + (r&15)*8 + (k&7)
//
// Hard invariants (measured):
//   - P row stride 264 shorts (528 B, 16B-aligned rows). 260 split every
//     odd-row ds_read_b128: 63.6 -> 86.5 µs (R8).
//   - XCD pinning everywhere (R2: FETCH 39.7->14.9 MB).
//   - attn 2-phase body at R9 form is the local optimum (R2/R5/R7/R10
//     triangulation); no reg additions beyond it (R4/R6/R10 spill cliffs).
// R24 (this round): cooperative MEGA-FUSION. Modeled rest ~40µs vs
//   measured ~95µs stable across all rowsum variants -> suspect per-launch/
//   drain overhead + Po round-trip. One hipLaunchCooperativeKernel,
//   256 blk x 1024 thr (1 blk/CU co-resident), grid.sync between stages:
//   wprep | proj (16-l tiles, 4 sub-blocks) | rowsum (R21) | attn (R9 body,
//   BOTH l-halves as wave-groups of one block; combine done in LDS).
//   Po buffer + combine kernel + 4 launches eliminated.

static __device__ __forceinline__ short f2bf(float f) {
    uint32_t u = __float_as_uint(f);
    u += 0x7fffu + ((u >> 16) & 1u);
    return (short)(u >> 16);
}

__global__ __launch_bounds__(1024) void mega_kernel(
    const float* __restrict__ x,
    const float* __restrict__ Wq, const float* __restrict__ bq,
    const float* __restrict__ Wk, const float* __restrict__ bk,
    const float* __restrict__ Wv, const float* __restrict__ bv,
    short* __restrict__ Qf, short* __restrict__ Kf, short* __restrict__ Vp,
    float* __restrict__ Dv, short* __restrict__ Wf,
    float* __restrict__ out)
{
    cg::grid_group grid = cg::this_grid();

    __shared__ union SH {
        short P2[2][2][64][264];   // attn: dbuf per l-half (135168 B)
        short Xb[4][16][136];      // proj: 4 sub-blocks x 16-l x 128c (+8 pad)
        float Db[16][32];          // rowsum partials
        float Rb[8192];            // epilogue lh-combine (32 KB)
    } sh;

    const int ib   = blockIdx.x;          // 0..255
    const int tid  = threadIdx.x;
    const int wave = tid >> 6;            // 0..15
    const int lane = tid & 63;
    const int quad = lane >> 4;
    const int mc   = lane & 15;
    const int l32  = lane & 31;
    const int h    = lane >> 5;

    // XCD pinning: blocks {i : (i>>1)&3 == n} land on XCD pair {2n,2n+1}
    const int n   = (ib >> 1) & 3;
    const int b64 = ((ib >> 3) << 1) | (ib & 1);   // 0..63 within n

    // ================= Stage 0: W prep =================
    {
        const int g = ib * 1024 + tid;    // 0..262143; work for g<49152
        if (g < 49152) {
            const int mat = g >> 14;
            const int rem = g & 16383;
            const int o   = rem >> 7;
            const int c   = rem & 127;
            const float* W = (mat == 0) ? Wq : (mat == 1) ? Wk : Wv;
            float v = W[o * CH + c];
            if (mat == 1) v *= 0.08838834764831845f;
            Wf[(size_t)mat * 16384 + (o >> 4) * 2048 + (c >> 5) * 512
               + ((c >> 3) & 3) * 128 + (o & 15) * 8 + (c & 7)] = f2bf(v);
        }
    }
    grid.sync();

    // ================= Stage 1: QKV projection =================
    // 4 sub-blocks of 256 thr; sub-block handles 16-l tile gt = b64*4+sub.
    {
        const int sub  = tid >> 8;        // 0..3
        const int stid = tid & 255;
        const int gt   = b64 * 4 + sub;   // 16-l tile of n (0..255)
        const int l0   = gt << 4;
        const int w4   = (tid >> 6) & 3;  // wave within sub-block

        {   // stage x -> LDS bf16 [l][c]
            const int sl = stid & 15;     // l
            const int cg = stid >> 4;     // c-group of 8 (0..15)
            const float* xp = x + ((size_t)n * CH + cg * 8) * LL + l0 + sl;
            short8 buf;
            #pragma unroll
            for (int i2 = 0; i2 < 8; ++i2)
                buf[i2] = f2bf(xp[(size_t)i2 * LL]);
            *(short8*)(void*)&sh.Xb[sub][sl][cg * 8] = buf;
        }
        __syncthreads();

        short8 xf[4];                     // B-frags: B[k=c][col=l]
        #pragma unroll
        for (int s = 0; s < 4; ++s)
            xf[s] = *(const short8*)(const void*)&sh.Xb[sub][mc][32 * s + quad * 8];

        const size_t obase = ((size_t)n * 256 + gt) * 2048;
        const float scale = 0.08838834764831845f;  // 1/sqrt(128)

        #pragma unroll
        for (int mat = 0; mat < 3; ++mat) {
            const short* Wm = Wf + (size_t)mat * 16384;
            const float* bb = (mat == 0) ? bq : (mat == 1) ? bk : bv;
            const float bscale = (mat == 1) ? scale : 1.0f;
            #pragma unroll
            for (int oo = 0; oo < 2; ++oo) {
                const int ot = w4 * 2 + oo;
                floatx4 acc = {0.f, 0.f, 0.f, 0.f};
                #pragma unroll
                for (int s = 0; s < 4; ++s)
                    acc = __builtin_amdgcn_mfma_f32_16x16x32_bf16(
                        *(const short8*)(const void*)(Wm + ot * 2048 + s * 512 + lane * 8),
                        xf[s], acc, 0, 0, 0);
                const int c0 = ot * 16 + 4 * quad;
                if (mat < 2) {
                    short4b pv;
                    #pragma unroll
                    for (int r = 0; r < 4; ++r)
                        pv[r] = f2bf(acc[r] + bb[c0 + r] * bscale);
                    short* dst = ((mat == 0) ? Qf : Kf) + obase
                               + (c0 >> 5) * 512 + ((c0 >> 3) & 3) * 128
                               + mc * 8 + (c0 & 7);
                    *(short4b*)(void*)dst = pv;
                } else {
                    #pragma unroll
                    for (int r = 0; r < 4; ++r)
                        Vp[obase + (c0 + r) * 16 + mc] = f2bf(acc[r] + bb[c0 + r]);
                }
            }
        }
    }
    grid.sync();

    // ================= Stage 2: rowsum -> rcpD (R21 form) =================
    {
        const int tq = b64;               // 64-l group
        const int mw = wave & 7;          // m-eighth
        const int th = wave >> 3;         // K-tile half

        const short* Kb = Kf + ((size_t)n * 256 + tq * 4 + th * 2) * 2048 + lane * 8;
        short8 kf[2][4];
        #pragma unroll
        for (int t = 0; t < 2; ++t)
            #pragma unroll
            for (int s = 0; s < 4; ++s)
                kf[t][s] = *(const short8*)(const void*)(Kb + t * 2048 + s * 512);

        const short* Qn = Qf + (size_t)n * 524288 + (size_t)mw * 32 * 2048 + lane * 8;
        float rs[2][4] = {{0.f, 0.f, 0.f, 0.f}, {0.f, 0.f, 0.f, 0.f}};

        for (int it = 0; it < 32; ++it) {
            short8 q[4];
            #pragma unroll
            for (int s = 0; s < 4; ++s)
                q[s] = *(const short8*)(const void*)(Qn + (size_t)it * 2048 + s * 512);
            floatx4 a0 = {0.f, 0.f, 0.f, 0.f};
            floatx4 a1 = {0.f, 0.f, 0.f, 0.f};
            #pragma unroll
            for (int s = 0; s < 4; ++s) {
                a0 = __builtin_amdgcn_mfma_f32_16x16x32_bf16(kf[0][s], q[s], a0, 0, 0, 0);
                a1 = __builtin_amdgcn_mfma_f32_16x16x32_bf16(kf[1][s], q[s], a1, 0, 0, 0);
            }
            #pragma unroll
            for (int r = 0; r < 4; ++r) {
                rs[0][r] += __expf(a0[r]);
                rs[1][r] += __expf(a1[r]);
            }
        }

        __syncthreads();   // Xb reuse guard (stage 1 reads done block-wide)
        #pragma unroll
        for (int t = 0; t < 2; ++t)
            #pragma unroll
            for (int r = 0; r < 4; ++r) {
                float v = rs[t][r];
                v += __shfl_xor(v, 1);
                v += __shfl_xor(v, 2);
                v += __shfl_xor(v, 4);
                v += __shfl_xor(v, 8);
                if (mc == 0) sh.Db[wave][t * 16 + quad * 4 + r] = v;
            }
        __syncthreads();
        if (tid < 64) {
            const int lhh = tid >> 5, lr = tid & 31;
            float s = 0.f;
            #pragma unroll
            for (int m = 0; m < 8; ++m) s += sh.Db[lhh * 8 + m][lr];
            Dv[(size_t)n * 4096 + tq * 64 + tid] = 1.0f / s;
        }
    }
    grid.sync();

    // ================= Stage 3: attention output (R9 body x 2 l-halves) ===
    {
        const int mb  = b64;              // m-block (0..63)
        const int m0  = mb << 6;
        const int w8  = wave & 7;         // wave within l-half group
        const int lh  = wave >> 3;        // l-half (waves 0-7: lh0, 8-15: lh1)
        const int ct  = w8 & 3;           // phase B c-tile
        const int mh  = w8 >> 2;          // phase B m-half

        const short* Qn  = Qf + (size_t)n * 524288;
        const short* Kn  = Kf + (size_t)n * 524288;
        const short* Vpn = Vp + (size_t)n * 524288;
        const float* Dn  = Dv + (size_t)n * 4096;
        const int tile0  = lh * 128;      // first 16-l tile of this half

        floatx16 acc;
        #pragma unroll
        for (int r = 0; r < 16; ++r) acc[r] = 0.f;

        for (int t = 0; t < 8; ++t) {
            const int p   = t & 1;
            const int tb0 = tile0 + t * 16;

            // ---- phase A: wave w8 -> l-tiles {2w8, 2w8+1}, 64 m ----
            {
                const int tb = tb0 + 2 * w8;
                short8 kfr[2][4];
                #pragma unroll
                for (int jj = 0; jj < 2; ++jj)
                    #pragma unroll
                    for (int s = 0; s < 4; ++s)
                        kfr[jj][s] = *(const short8*)(const void*)(
                            Kn + (size_t)(tb + jj) * 2048 + s * 512 + lane * 8);
                floatx4 dr[2];
                #pragma unroll
                for (int jj = 0; jj < 2; ++jj)
                    dr[jj] = *(const floatx4*)(const void*)(
                        Dn + (tb + jj) * 16 + quad * 4);

                #pragma unroll
                for (int mst = 0; mst < 4; ++mst) {
                    short8 qt[4];
                    #pragma unroll
                    for (int s = 0; s < 4; ++s)
                        qt[s] = *(const short8*)(const void*)(
                            Qn + (size_t)((m0 >> 4) + mst) * 2048 + s * 512 + lane * 8);
                    floatx4 sa0 = {0.f, 0.f, 0.f, 0.f};
                    floatx4 sa1 = {0.f, 0.f, 0.f, 0.f};
                    #pragma unroll
                    for (int s = 0; s < 4; ++s) {
                        sa0 = __builtin_amdgcn_mfma_f32_16x16x32_bf16(kfr[0][s], qt[s], sa0, 0, 0, 0);
                        sa1 = __builtin_amdgcn_mfma_f32_16x16x32_bf16(kfr[1][s], qt[s], sa1, 0, 0, 0);
                    }
                    short4b pv0, pv1;
                    #pragma unroll
                    for (int r = 0; r < 4; ++r) {
                        pv0[r] = f2bf(__expf(sa0[r]) * dr[0][r]);
                        pv1[r] = f2bf(__expf(sa1[r]) * dr[1][r]);
                    }
                    // C-layout (row=l=4q+r, col=m=mc) -> P[m][l-local]
                    *(short4b*)(void*)&sh.P2[lh][p][16 * mst + mc][32 * w8 + quad * 4] = pv0;
                    *(short4b*)(void*)&sh.P2[lh][p][16 * mst + mc][32 * w8 + 16 + quad * 4] = pv1;
                }
            }
            __syncthreads();   // both halves: P[lh][p] visible

            // ---- phase B: wave (ct,mh): full 256-l sum, 16 chunks ----
            #pragma unroll
            for (int kc = 0; kc < 16; ++kc) {
                const short8 vf = *(const short8*)(const void*)(
                    Vpn + (size_t)(tb0 + kc) * 2048
                        + (32 * ct + l32) * 16 + 8 * h);
                const short8 pf = *(const short8*)(const void*)
                    &sh.P2[lh][p][32 * mh + l32][16 * kc + 8 * h];
                acc = __builtin_amdgcn_mfma_f32_32x32x16_bf16(vf, pf, acc, 0, 0, 0);
            }
            // no trailing barrier: next step writes P[lh][p^1]
        }

        // ---- epilogue: lh=1 hands its partial to lh=0 via LDS ----
        __syncthreads();
        if (lh == 1)
            *(floatx16*)(void*)&sh.Rb[(w8 * 64 + lane) * 16] = acc;
        __syncthreads();
        if (lh == 0) {
            const floatx16 o = *(const floatx16*)(const void*)
                &sh.Rb[(w8 * 64 + lane) * 16];
            #pragma unroll
            for (int r = 0; r < 16; ++r) {
                const int c = 32 * ct + (r & 3) + 8 * (r >> 2) + 4 * h;
                const int m = m0 + 32 * mh + l32;
                const size_t idx = ((size_t)n * CH + c) * LL + m;
                out[idx] = x[idx] + acc[r] + o[r];
            }
        }
    }
}

// ---------------------------------------------------------------------------
extern "C" void kernel_launch(void* const* d_in, const int* in_sizes, int n_in,
                              void* d_out, int out_size, void* d_ws, size_t ws_size,
                              hipStream_t stream) {
    (void)in_sizes; (void)n_in; (void)out_size; (void)ws_size;
    const float* x  = (const float*)d_in[0];
    const float* Wq = (const float*)d_in[1];
    const float* bq = (const float*)d_in[2];
    const float* Wk = (const float*)d_in[3];
    const float* bk = (const float*)d_in[4];
    const float* Wv = (const float*)d_in[5];
    const float* bv = (const float*)d_in[6];
    float* out = (float*)d_out;

    char* ws = (char*)d_ws;
    // ws: Qf 4MB | Kf 4MB | Vp 4MB | Dv 64KB | Wf 96KB  (~12.7 MB)
    short* Qf = (short*)(ws);
    short* Kf = (short*)(ws + 4194304);
    short* Vp = (short*)(ws + 8388608);
    float* Dv = (float*)(ws + 12582912);
    short* Wf = (short*)(ws + 16777216);

    void* args[] = {
        (void*)&x, (void*)&Wq, (void*)&bq, (void*)&Wk, (void*)&bk,
        (void*)&Wv, (void*)&bv, (void*)&Qf, (void*)&Kf, (void*)&Vp,
        (void*)&Dv, (void*)&Wf, (void*)&out
    };
    hipLaunchCooperativeKernel((const void*)mega_kernel,
                               dim3(256), dim3(1024), args, 0, stream);
}

// Round 12
// 162.654 us; speedup vs baseline: 1.5226x; 1.5226x over previous
//
#include <hip/hip_runtime.h>
#include <hip/hip_bf16.h>
#include <stdint.h>

// Problem constants (N,C,H,W = 4,128,64,64)
#define NB 4
#define CH 128
#define LL 4096   // H*W

typedef __attribute__((ext_vector_type(8))) short short8;   // 8 bf16 MFMA A/B frag (4 VGPR)
typedef __attribute__((ext_vector_type(4))) short short4b;  // 4 bf16 (8B)
typedef __attribute__((ext_vector_type(4))) float floatx4;  // 16x16 C/D frag
typedef __attribute__((ext_vector_type(16))) float floatx16; // 32x32 C/D frag

// Frag-major layout (verified R9-R13): element (row r, k) of 16-wide tile t:
//   t*2048 + (k>>5)*512 + ((k>>3)&3)*128 + (r&15)*8 + (k&7)
//
// Hard invariants (measured this session):
//   - P row stride 264 shorts (528 B, 16B-aligned rows). 260 (8 mod 16)
//     split every odd-row ds_read_b128: 63.6 -> 86.5 µs. Alignment >> the
//     4-way bank conflict 264 carries (~immaterial, 1.05M cycles).
//   - XCD pinning everywhere (FETCH 39.7->14.9 MB).
//   - l-split co-residency, 2 blocks/CU (73 -> 63.6 µs).
//   - No reg additions to attn beyond this form: +8..32 live VGPRs hits
//     the 128-cap spill cliff (FETCH 17.5->21.8..137 MB; 3 independent
//     reproductions).
//   - attn 2-phase body IS the local optimum: traffic -2.7x (flat),
//     resident-Q (-40% loads, +25% time), dual-acc / V-prefetch / T5
//     setprio (all spill or neutral), smaller intervals (+54%).
//   - Cooperative mega-fusion refuted: fused GPU time 165 µs > 5-kernel
//     sum ~100 (lost co-residency + grid.sync pacing) + ~82 µs coop-launch
//     overhead.
// R25: pure restore of the R9 optimum (best attn 61.4 µs; total within
// noise of session best 157.8).

static __device__ __forceinline__ short f2bf(float f) {
    uint32_t u = __float_as_uint(f);
    u += 0x7fffu + ((u >> 16) & 1u);
    return (short)(u >> 16);
}

// ---------------------------------------------------------------------------
// Kernel 0: W prep — Wq/Wk/Wv fp32 [o][c] -> bf16 frag-major A-layout
// (rows=o, k=c). K-scale folded into Wk.
// ---------------------------------------------------------------------------
__global__ __launch_bounds__(256) void wprep_kernel(
    const float* __restrict__ Wq, const float* __restrict__ Wk,
    const float* __restrict__ Wv, short* __restrict__ Wf)
{
    const int g = blockIdx.x * 256 + threadIdx.x;   // 0..49151
    const int mat = g >> 14;
    const int rem = g & 16383;
    const int o   = rem >> 7;
    const int c   = rem & 127;
    const float* W = (mat == 0) ? Wq : (mat == 1) ? Wk : Wv;
    float v = W[o * CH + c];
    if (mat == 1) v *= 0.08838834764831845f;
    Wf[(size_t)mat * 16384 + (o >> 4) * 2048 + (c >> 5) * 512
       + ((c >> 3) & 3) * 128 + (o & 15) * 8 + (c & 7)] = f2bf(v);
}

// ---------------------------------------------------------------------------
// Kernel 1: QKV projection via MFMA (R12-proven structure).
// Outputs Qf/Kf frag-major, Vp panel [n][l>>4][c][l&15].
// grid = 512 blocks x 256 thr. XCD-pinned block remap.
// ---------------------------------------------------------------------------
__global__ __launch_bounds__(256) void proj_kernel(
    const float* __restrict__ x, const short* __restrict__ Wf,
    const float* __restrict__ bq, const float* __restrict__ bk,
    const float* __restrict__ bv,
    short* __restrict__ Qf, short* __restrict__ Kf, short* __restrict__ Vp)
{
    const int i    = blockIdx.x;
    const int n    = (i >> 1) & 3;            // XCD pair {2n,2n+1}
    const int lt   = ((i >> 3) << 1) | (i & 1); // l-tile of 32 (0..127)
    const int l0   = lt << 5;
    const int tid  = threadIdx.x;
    const int wave = tid >> 6;        // 0..3
    const int lane = tid & 63;
    const int quad = lane >> 4;
    const int mc   = lane & 15;

    __shared__ short Xb[32][136];     // [l][c] bf16, +8 pad (8.7 KB)

    {
        const int sl = tid & 31;      // l
        const int cg = tid >> 5;      // c-group of 16 (0..7)
        const float* xp = x + ((size_t)n * CH + cg * 16) * LL + l0 + sl;
        short8 buf;
        #pragma unroll
        for (int i2 = 0; i2 < 16; ++i2) {
            buf[i2 & 7] = f2bf(xp[(size_t)i2 * LL]);
            if ((i2 & 7) == 7)
                *(short8*)(void*)&Xb[sl][cg * 16 + (i2 & 8)] = buf;
        }
    }
    __syncthreads();

    const int lt2 = wave >> 1;        // l-subtile of 16
    const int oh  = wave & 1;         // o-half (4 o-tiles)
    const int gt  = lt * 2 + lt2;     // global 16-l tile index

    short8 xf[4];                     // B-frags: B[k=c][col=l]
    #pragma unroll
    for (int s = 0; s < 4; ++s)
        xf[s] = *(const short8*)(const void*)&Xb[lt2 * 16 + mc][32 * s + quad * 8];

    const size_t obase = ((size_t)n * 256 + gt) * 2048;
    const float scale = 0.08838834764831845f;  // 1/sqrt(128)

    #pragma unroll
    for (int mat = 0; mat < 3; ++mat) {
        const short* Wm = Wf + (size_t)mat * 16384;
        const float* bb = (mat == 0) ? bq : (mat == 1) ? bk : bv;
        const float bscale = (mat == 1) ? scale : 1.0f;
        #pragma unroll
        for (int ot = oh * 4; ot < oh * 4 + 4; ++ot) {
            floatx4 acc = {0.f, 0.f, 0.f, 0.f};
            #pragma unroll
            for (int s = 0; s < 4; ++s)
                acc = __builtin_amdgcn_mfma_f32_16x16x32_bf16(
                    *(const short8*)(const void*)(Wm + ot * 2048 + s * 512 + lane * 8),
                    xf[s], acc, 0, 0, 0);
            const int c0 = ot * 16 + 4 * quad;
            if (mat < 2) {
                short4b pv;
                #pragma unroll
                for (int r = 0; r < 4; ++r)
                    pv[r] = f2bf(acc[r] + bb[c0 + r] * bscale);
                short* dst = ((mat == 0) ? Qf : Kf) + obase
                           + (c0 >> 5) * 512 + ((c0 >> 3) & 3) * 128
                           + mc * 8 + (c0 & 7);
                *(short4b*)(void*)dst = pv;
            } else {
                #pragma unroll
                for (int r = 0; r < 4; ++r)
                    Vp[obase + (c0 + r) * 16 + mc] = f2bf(acc[r] + bb[c0 + r]);
            }
        }
    }
}

// ---------------------------------------------------------------------------
// Kernel 2 (R21, frozen): softmax denominators -> rcpD[n][l].
// 256 blocks x 1024 thr; block = 4 K-tiles; wave (mw,th): m-eighth x
// K-tile pair, kf[2][4] resident, one q-tile per iteration.
// ---------------------------------------------------------------------------
__global__ __launch_bounds__(1024) void rowsum_kernel(
    const short* __restrict__ Qf, const short* __restrict__ Kf,
    float* __restrict__ Dv)
{
    const int i    = blockIdx.x;         // 256 blocks
    const int n    = (i >> 1) & 3;       // XCD pair {2n,2n+1}
    const int tq   = ((i >> 3) << 1) | (i & 1);  // 64-l group (0..63)
    const int tid  = threadIdx.x;
    const int wave = tid >> 6;           // 0..15
    const int lane = tid & 63;
    const int quad = lane >> 4;
    const int mc   = lane & 15;
    const int mw   = wave & 7;           // m-eighth (512 m = 32 q-tiles)
    const int th   = wave >> 3;          // K-tile half (2 of the 4 tiles)

    __shared__ float Db[16][32];         // per-wave partial D (2 KB)

    const short* Kb = Kf + ((size_t)n * 256 + tq * 4 + th * 2) * 2048 + lane * 8;
    short8 kf[2][4];
    #pragma unroll
    for (int t = 0; t < 2; ++t)
        #pragma unroll
        for (int s = 0; s < 4; ++s)
            kf[t][s] = *(const short8*)(const void*)(Kb + t * 2048 + s * 512);

    const short* Qn = Qf + (size_t)n * 524288 + (size_t)mw * 32 * 2048 + lane * 8;
    float rs[2][4] = {{0.f, 0.f, 0.f, 0.f}, {0.f, 0.f, 0.f, 0.f}};

    for (int it = 0; it < 32; ++it) {
        short8 q[4];
        #pragma unroll
        for (int s = 0; s < 4; ++s)
            q[s] = *(const short8*)(const void*)(
                Qn + (size_t)it * 2048 + s * 512);
        floatx4 a0 = {0.f, 0.f, 0.f, 0.f};
        floatx4 a1 = {0.f, 0.f, 0.f, 0.f};
        #pragma unroll
        for (int s = 0; s < 4; ++s) {
            a0 = __builtin_amdgcn_mfma_f32_16x16x32_bf16(kf[0][s], q[s], a0, 0, 0, 0);
            a1 = __builtin_amdgcn_mfma_f32_16x16x32_bf16(kf[1][s], q[s], a1, 0, 0, 0);
        }
        #pragma unroll
        for (int r = 0; r < 4; ++r) {
            rs[0][r] += __expf(a0[r]);
            rs[1][r] += __expf(a1[r]);
        }
    }

    // reduce over m within wave (cols live in mc lanes), then across 8 m-waves
    #pragma unroll
    for (int t = 0; t < 2; ++t)
        #pragma unroll
        for (int r = 0; r < 4; ++r) {
            float v = rs[t][r];
            v += __shfl_xor(v, 1);
            v += __shfl_xor(v, 2);
            v += __shfl_xor(v, 4);
            v += __shfl_xor(v, 8);
            if (mc == 0) Db[wave][t * 16 + quad * 4 + r] = v;
        }
    __syncthreads();
    if (tid < 64) {
        const int lh = tid >> 5, lr = tid & 31;
        float s = 0.f;
        #pragma unroll
        for (int m = 0; m < 8; ++m) s += Db[lh * 8 + m][lr];
        Dv[(size_t)n * 4096 + tq * 64 + tid] = 1.0f / s;
    }
}

// ---------------------------------------------------------------------------
// Kernel 3 (R9 form — measured 61.4 µs, the local optimum): partial O
// over an l-half. grid 512 = {n, m-block 64, l-half} x 512 thr (8 waves),
// 2 blocks/CU. 8 steps of 256 l; phase A: wave w -> l-tiles 2w,2w+1
// (Q per-step, L1/L2-hot); phase B: wave (ct,mh) -> full 256-l sum,
// single acc. P stride 264 (REQUIRED 16B row alignment).
// Writes partial O f32 to Po[lh][n][c][m].
// ---------------------------------------------------------------------------
__global__ __launch_bounds__(512, 4) void attn_out_kernel(
    const short* __restrict__ Qf, const short* __restrict__ Kf,
    const short* __restrict__ Vp, const float* __restrict__ Dv,
    float* __restrict__ Po)
{
    const int i    = blockIdx.x;
    const int n    = (i >> 1) & 3;               // XCD pair {2n,2n+1}
    const int j    = ((i >> 3) << 1) | (i & 1);  // 0..127
    const int lh   = j >> 6;                     // l-half
    const int mb   = j & 63;                     // m-block (0..63)
    const int m0   = mb << 6;
    const int tid  = threadIdx.x;
    const int wave = tid >> 6;          // 0..7
    const int lane = tid & 63;
    const int quad = lane >> 4;
    const int mc   = lane & 15;
    const int l32  = lane & 31;
    const int h    = lane >> 5;
    const int ct   = wave & 3;          // phase B c-tile (32 channels)
    const int mh   = wave >> 2;         // phase B m-half (32 cols)

    __shared__ short P[2][64][264];     // dbuf [m][l-local 256 +8] (66 KB)

    const short* Qn  = Qf + (size_t)n * 524288;
    const short* Kn  = Kf + (size_t)n * 524288;
    const short* Vpn = Vp + (size_t)n * 524288;
    const float* Dn  = Dv + (size_t)n * 4096;
    const int tile0  = lh * 128;        // first 16-l tile of this half

    floatx16 acc;
    #pragma unroll
    for (int r = 0; r < 16; ++r) acc[r] = 0.f;

    for (int t = 0; t < 8; ++t) {
        const int p = t & 1;

        // ---- phase A: wave w -> l-tiles {2w, 2w+1} of step t, 64 m ----
        {
            const int tb = tile0 + t * 16 + 2 * wave;
            short8 kfr[2][4];
            #pragma unroll
            for (int jj = 0; jj < 2; ++jj)
                #pragma unroll
                for (int s = 0; s < 4; ++s)
                    kfr[jj][s] = *(const short8*)(const void*)(
                        Kn + (size_t)(tb + jj) * 2048 + s * 512 + lane * 8);
            floatx4 dr[2];
            #pragma unroll
            for (int jj = 0; jj < 2; ++jj)
                dr[jj] = *(const floatx4*)(const void*)(
                    Dn + (tb + jj) * 16 + quad * 4);

            #pragma unroll
            for (int mst = 0; mst < 4; ++mst) {
                short8 qt[4];
                #pragma unroll
                for (int s = 0; s < 4; ++s)
                    qt[s] = *(const short8*)(const void*)(
                        Qn + (size_t)((m0 >> 4) + mst) * 2048 + s * 512 + lane * 8);
                floatx4 sa0 = {0.f, 0.f, 0.f, 0.f};
                floatx4 sa1 = {0.f, 0.f, 0.f, 0.f};
                #pragma unroll
                for (int s = 0; s < 4; ++s) {
                    sa0 = __builtin_amdgcn_mfma_f32_16x16x32_bf16(kfr[0][s], qt[s], sa0, 0, 0, 0);
                    sa1 = __builtin_amdgcn_mfma_f32_16x16x32_bf16(kfr[1][s], qt[s], sa1, 0, 0, 0);
                }
                short4b pv0, pv1;
                #pragma unroll
                for (int r = 0; r < 4; ++r) {
                    pv0[r] = f2bf(__expf(sa0[r]) * dr[0][r]);
                    pv1[r] = f2bf(__expf(sa1[r]) * dr[1][r]);
                }
                // C-layout (row=l=4q+r, col=m=mc) -> P[m][l-local]
                *(short4b*)(void*)&P[p][16 * mst + mc][32 * wave + quad * 4] = pv0;
                *(short4b*)(void*)&P[p][16 * mst + mc][32 * wave + 16 + quad * 4] = pv1;
            }
        }
        __syncthreads();   // only barrier: P[p] visible

        // ---- phase B: wave (ct,mh): full 256-l sum, 16 chunks ----
        #pragma unroll
        for (int kc = 0; kc < 16; ++kc) {
            const short8 vf = *(const short8*)(const void*)(
                Vpn + (size_t)(tile0 + t * 16 + kc) * 2048
                    + (32 * ct + l32) * 16 + 8 * h);
            const short8 pf = *(const short8*)(const void*)&P[p][32 * mh + l32][16 * kc + 8 * h];
            acc = __builtin_amdgcn_mfma_f32_32x32x16_bf16(vf, pf, acc, 0, 0, 0);
        }
        // no trailing barrier: next step writes P[p^1]
    }

    // ---- epilogue: write partial O (f32), 32x32 C-layout ----
    float* Pon = Po + (size_t)(lh * 4 + n) * 524288;  // [lh][n][c][m]
    #pragma unroll
    for (int r = 0; r < 16; ++r) {
        const int c = 32 * ct + (r & 3) + 8 * (r >> 2) + 4 * h;
        const int m = m0 + 32 * mh + l32;
        Pon[(size_t)c * LL + m] = acc[r];
    }
}

// ---------------------------------------------------------------------------
// Kernel 4: out = x + Po[0] + Po[1], XCD-pinned.
// grid 2048 x 256 thr (1 float4/thread).
// ---------------------------------------------------------------------------
__global__ __launch_bounds__(256) void combine_kernel(
    const float* __restrict__ x, const float* __restrict__ Po,
    float* __restrict__ out)
{
    const int i = blockIdx.x;
    const int n = (i >> 1) & 3;                  // XCD pair {2n,2n+1}
    const int j = ((i >> 3) << 1) | (i & 1);     // 0..511 within n
    const size_t k = ((size_t)((n << 9) | j)) * 256 + threadIdx.x;  // float4 idx
    const floatx4 a = *(const floatx4*)(const void*)(x + 4 * k);
    const floatx4 b = *(const floatx4*)(const void*)(Po + 4 * k);
    const floatx4 c = *(const floatx4*)(const void*)(Po + 2097152 + 4 * k);
    floatx4 o;
    #pragma unroll
    for (int r = 0; r < 4; ++r) o[r] = a[r] + b[r] + c[r];
    *(floatx4*)(void*)(out + 4 * k) = o;
}

// ---------------------------------------------------------------------------
extern "C" void kernel_launch(void* const* d_in, const int* in_sizes, int n_in,
                              void* d_out, int out_size, void* d_ws, size_t ws_size,
                              hipStream_t stream) {
    (void)in_sizes; (void)n_in; (void)out_size; (void)ws_size;
    const float* x  = (const float*)d_in[0];
    const float* Wq = (const float*)d_in[1];
    const float* bq = (const float*)d_in[2];
    const float* Wk = (const float*)d_in[3];
    const float* bk = (const float*)d_in[4];
    const float* Wv = (const float*)d_in[5];
    const float* bv = (const float*)d_in[6];
    float* out = (float*)d_out;

    char* ws = (char*)d_ws;
    // ws: Qf 4MB | Kf 4MB | Vp 4MB | Dv 64KB | Wf 96KB+pad | Po 16MB (~33MB)
    short* Qf = (short*)(ws);
    short* Kf = (short*)(ws + 4194304);
    short* Vp = (short*)(ws + 8388608);
    float* Dv = (float*)(ws + 12582912);
    short* Wf = (short*)(ws + 16777216);
    float* Po = (float*)(ws + 16908288);

    wprep_kernel<<<192, 256, 0, stream>>>(Wq, Wk, Wv, Wf);
    proj_kernel<<<512, 256, 0, stream>>>(x, Wf, bq, bk, bv, Qf, Kf, Vp);
    rowsum_kernel<<<256, 1024, 0, stream>>>(Qf, Kf, Dv);
    attn_out_kernel<<<512, 512, 0, stream>>>(Qf, Kf, Vp, Dv, Po);
    combine_kernel<<<2048, 256, 0, stream>>>(x, Po, out);
}